// Round 3
// baseline (392.333 us; speedup 1.0000x reference)
//
#include <hip/hip_runtime.h>

#define DEVI __device__ __forceinline__

typedef __attribute__((ext_vector_type(8))) short short8;
typedef __attribute__((ext_vector_type(4))) float f32x4;
typedef unsigned short u16;

DEVI u16 f2bf(float f){
  unsigned int u = __float_as_uint(f);
  unsigned int r = (u + 0x7FFFu + ((u>>16)&1u)) >> 16;
  return (u16)r;
}
DEVI float bf2f(u16 h){ return __uint_as_float(((unsigned int)h)<<16); }

DEVI float gelu_f(float x){
  float x3 = x*x*x;
  float t = tanhf(0.7978845608028654f*(x + 0.044715f*x3));
  return 0.5f*x*(1.0f + t);
}

DEVI void async_cp16(const void* g, void* l){
  __builtin_amdgcn_global_load_lds(
      (const __attribute__((address_space(1))) unsigned int*)g,
      (__attribute__((address_space(3))) unsigned int*)l, 16, 0, 0);
}

// ---------------- weight transpose + bf16 convert: w (K x N) f32 -> wt (N x K) bf16
__global__ __launch_bounds__(256) void wtrans_k(const float* __restrict__ w,
                                                u16* __restrict__ wt, int K, int N){
  __shared__ float tile[32][33];
  int tn = blockIdx.x*32, tk = blockIdx.y*32;
  int r = threadIdx.x>>3, c4 = (threadIdx.x&7)*4;
  float4 vv = *(const float4*)&w[(size_t)(tk+r)*N + tn + c4];
  tile[r][c4+0]=vv.x; tile[r][c4+1]=vv.y; tile[r][c4+2]=vv.z; tile[r][c4+3]=vv.w;
  __syncthreads();
  u16 o[4];
  #pragma unroll
  for (int j=0;j<4;j++) o[j] = f2bf(tile[c4+j][r]);
  unsigned long long pk = (unsigned long long)o[0] | ((unsigned long long)o[1]<<16)
                        | ((unsigned long long)o[2]<<32) | ((unsigned long long)o[3]<<48);
  *(unsigned long long*)&wt[(size_t)(tn+r)*K + tk + c4] = pk;
}

// ---------------- LN1: x f32 (4096x768) -> xin bf16
__global__ __launch_bounds__(256) void ln1_k(const float* __restrict__ x,
                                             const float* __restrict__ sc,
                                             u16* __restrict__ xin){
  int row = blockIdx.x, tid = threadIdx.x;
  const float* xr = x + (size_t)row*768;
  float v[3]; float s=0.f, ss=0.f;
  #pragma unroll
  for (int i=0;i<3;i++){ v[i]=xr[tid+i*256]; s+=v[i]; ss+=v[i]*v[i]; }
  #pragma unroll
  for (int m=1;m<=32;m<<=1){ s += __shfl_xor(s,m,64); ss += __shfl_xor(ss,m,64); }
  __shared__ float ls0[4], ls1_[4];
  int w = tid>>6;
  if ((tid&63)==0){ ls0[w]=s; ls1_[w]=ss; }
  __syncthreads();
  s = ls0[0]+ls0[1]+ls0[2]+ls0[3]; ss = ls1_[0]+ls1_[1]+ls1_[2]+ls1_[3];
  float mu = s*(1.f/768.f);
  float var = ss*(1.f/768.f) - mu*mu;
  float inv = rsqrtf(var + 1e-6f);
  #pragma unroll
  for (int i=0;i<3;i++){ int c=tid+i*256; xin[(size_t)row*768+c] = f2bf((v[i]-mu)*inv*sc[c]); }
}

// ---------------- GEMM: C(MxN) = A(MxK,bf16) * Bt(NxK,bf16)^T
// EPI 0: f32 partial plane (split-K)   EPI 2: bf16(gelu(acc+bias))   EPI 3: plain bf16
template<int EPI, int SPLITK>
__global__ __launch_bounds__(256) void gemm_k(
    const u16* __restrict__ A, const u16* __restrict__ Bt,
    int M, int N, int K,
    float* __restrict__ Cf, u16* __restrict__ Cb,
    const float* __restrict__ bias)
{
  __shared__ __align__(16) u16 Al[128*32];
  __shared__ __align__(16) u16 Bl[128*32];
  const int tid = threadIdx.x, w = tid>>6, l = tid&63;
  const int m0 = blockIdx.y*128, n0 = blockIdx.x*128;
  const int Ksub = K/SPLITK;
  const int kc = (SPLITK>1) ? blockIdx.z : 0;
  const int kbase = kc*Ksub;
  const int wr = (w>>1)*64, wc = (w&1)*64;
  f32x4 acc[4][4];
  #pragma unroll
  for (int i=0;i<4;i++)
    #pragma unroll
    for (int j=0;j<4;j++){ f32x4 z={0.f,0.f,0.f,0.f}; acc[i][j]=z; }
  const int lr = l>>2, lc = l&3;
  for (int k0=0; k0<Ksub; k0+=32){
    __syncthreads();
    #pragma unroll
    for (int it=0; it<2; ++it){
      int arow = w*32 + it*16;
      async_cp16(A  + (size_t)(m0+arow+lr)*K + kbase + k0 + lc*8, &Al[arow*32]);
      async_cp16(Bt + (size_t)(n0+arow+lr)*K + kbase + k0 + lc*8, &Bl[arow*32]);
    }
    __syncthreads();
    short8 af[4], bfr[4];
    #pragma unroll
    for (int mi=0;mi<4;++mi) af[mi]  = *(const short8*)&Al[(wr+mi*16+(l&15))*32 + (l>>4)*8];
    #pragma unroll
    for (int ni=0;ni<4;++ni) bfr[ni] = *(const short8*)&Bl[(wc+ni*16+(l&15))*32 + (l>>4)*8];
    #pragma unroll
    for (int mi=0;mi<4;++mi)
      #pragma unroll
      for (int ni=0;ni<4;++ni)
        acc[mi][ni] = __builtin_amdgcn_mfma_f32_16x16x32_bf16(af[mi], bfr[ni], acc[mi][ni], 0,0,0);
  }
  #pragma unroll
  for (int mi=0;mi<4;++mi){
    int rb = m0 + wr + mi*16 + ((l>>4)<<2);
    #pragma unroll
    for (int ni=0;ni<4;++ni){
      int col = n0 + wc + ni*16 + (l&15);
      #pragma unroll
      for (int r=0;r<4;r++){
        int row = rb + r;
        float v = acc[mi][ni][r];
        if (EPI==0)      Cf[((size_t)kc*M + row)*N + col] = v;
        else if (EPI==2) Cb[(size_t)row*N+col] = f2bf(gelu_f(v + bias[col]));
        else             Cb[(size_t)row*N+col] = f2bf(v);
      }
    }
  }
}

// ---------------- split-K reduce + bias/ls/resid + LN2 + gelu (out-proj path)
__global__ __launch_bounds__(256) void redln_k(
    const float* __restrict__ P, const float* __restrict__ bias,
    const float* __restrict__ lsc, const float* __restrict__ resid,
    const float* __restrict__ ln2sc, const float* __restrict__ ln2bi,
    float* __restrict__ x0, u16* __restrict__ x1)
{
  const size_t MN = 4096ull*768;
  int row = blockIdx.x, tid = threadIdx.x;
  float v[3]; float s=0.f, ss=0.f;
  #pragma unroll
  for (int i=0;i<3;i++){
    int c = tid + i*256;
    size_t idx = (size_t)row*768 + c;
    float acc = P[idx] + P[MN+idx] + P[2*MN+idx] + P[3*MN+idx];
    float y = lsc[c]*(acc + bias[c]) + resid[idx];
    x0[idx] = y;
    v[i] = y; s += y; ss += y*y;
  }
  #pragma unroll
  for (int m=1;m<=32;m<<=1){ s += __shfl_xor(s,m,64); ss += __shfl_xor(ss,m,64); }
  __shared__ float ls0[4], ls1_[4];
  int w = tid>>6;
  if ((tid&63)==0){ ls0[w]=s; ls1_[w]=ss; }
  __syncthreads();
  s = ls0[0]+ls0[1]+ls0[2]+ls0[3]; ss = ls1_[0]+ls1_[1]+ls1_[2]+ls1_[3];
  float mu = s*(1.f/768.f);
  float var = ss*(1.f/768.f) - mu*mu;
  float inv = rsqrtf(var + 1e-6f);
  #pragma unroll
  for (int i=0;i<3;i++){
    int c = tid + i*256;
    float y = (v[i]-mu)*inv*ln2sc[c] + ln2bi[c];
    x1[(size_t)row*768 + c] = f2bf(gelu_f(y));
  }
}

// ---------------- split-K reduce + bias/ls/resid (final output)
__global__ __launch_bounds__(256) void red_k(
    const float* __restrict__ P, const float* __restrict__ bias,
    const float* __restrict__ lsc, const float* __restrict__ resid,
    float* __restrict__ out)
{
  const size_t MN = 4096ull*768;
  size_t i = ((size_t)blockIdx.x*256 + threadIdx.x)*4;
  int c = (int)(i % 768);
  float4 a0 = *(const float4*)&P[i];
  float4 a1 = *(const float4*)&P[MN+i];
  float4 a2 = *(const float4*)&P[2*MN+i];
  float4 a3 = *(const float4*)&P[3*MN+i];
  float4 bi = *(const float4*)&bias[c];
  float4 ls = *(const float4*)&lsc[c];
  float4 rs = *(const float4*)&resid[i];
  float4 o;
  o.x = ls.x*(a0.x+a1.x+a2.x+a3.x + bi.x) + rs.x;
  o.y = ls.y*(a0.y+a1.y+a2.y+a3.y + bi.y) + rs.y;
  o.z = ls.z*(a0.z+a1.z+a2.z+a3.z + bi.z) + rs.z;
  o.w = ls.w*(a0.w+a1.w+a2.w+a3.w + bi.w) + rs.w;
  *(float4*)&out[i] = o;
}

// ---------------- qkv postprocess: rms + rope + layout split
// V tensors are written TRANSPOSED: [seq][h][d=64][L]
__global__ __launch_bounds__(256) void postproc_k(
  const u16* __restrict__ qkv, const float* __restrict__ sincos,
  const float* __restrict__ aq, const float* __restrict__ ak,
  const float* __restrict__ aqs, const float* __restrict__ aks,
  u16* __restrict__ qg, u16* __restrict__ kg, u16* __restrict__ vg,
  u16* __restrict__ qsg, u16* __restrict__ ksg, u16* __restrict__ vsg)
{
  int m = blockIdx.x;
  int b = m>>11, v = (m>>9)&3, t = m&511;
  int w = threadIdx.x>>6, l = threadIdx.x&63;
  for (int inst = w; inst < 72; inst += 4){
    int tt = inst/12, h = inst - tt*12;
    float val = bf2f(qkv[(size_t)m*4608 + tt*768 + h*64 + l]);
    size_t gidx = (((size_t)(b*12) + h)*2048 + v*512 + t)*64 + l;
    size_t sidx = (((size_t)((v*2+b)*12) + h)*512 + t)*64 + l;
    if (tt==2){ vg[(((size_t)(b*12) + h)*64 + l)*2048 + v*512 + t] = f2bf(val); continue; }
    if (tt==5){ vsg[(((size_t)((v*2+b)*12) + h)*64 + l)*512 + t] = f2bf(val); continue; }
    float ss = val*val;
    #pragma unroll
    for (int mm=1;mm<=32;mm<<=1) ss += __shfl_xor(ss,mm,64);
    float mag = sqrtf(ss*(1.f/64.f) + 1e-5f);
    const float* al = (tt==0)?aq:(tt==1)?ak:(tt==3)?aqs:aks;
    val = al[h*64+l]*val/mag;
    float cs = sincos[((size_t)t*64 + l)*2];
    float sn = sincos[((size_t)t*64 + l)*2 + 1];
    float partner = __shfl_xor(val, 1, 64);
    float rot = (l&1) ? partner : -partner;
    val = val*cs + rot*sn;
    u16 bv = f2bf(val);
    if (tt==0) qg[gidx] = bv;
    else if (tt==1) kg[gidx] = bv;
    else if (tt==3) qsg[sidx] = bv;
    else ksg[sidx] = bv;
  }
}

// ---------------- merged segment-masked flash attention (both passes, one launch)
// Q/K: [seq][h][L][64] bf16 ; Vt: [seq][h][64][L] bf16 ; Out bf16 [4096][1536]
// No K/V LDS staging: fragments are loaded straight from global (L2-resident).
// Only per-wave P roundtrip uses LDS -> zero barriers in the whole kernel.
__global__ __launch_bounds__(256) void attn2_k(
  const u16* __restrict__ Qg, const u16* __restrict__ Kg, const u16* __restrict__ Vtg,
  const u16* __restrict__ Qs, const u16* __restrict__ Ks, const u16* __restrict__ Vts,
  u16* __restrict__ Out, const int* __restrict__ pids)
{
  __shared__ __align__(16) u16 Pl[4][16*64];
  const int gid = blockIdx.x;
  const int lid = (gid & 7)*192 + (gid >> 3);   // XCD-chunked swizzle (1536 = 8*192)
  const int tid = threadIdx.x, w = tid>>6, l = tid&63;
  const u16 *Q, *K, *Vt; const int* prow;
  int L, seq, h, qb, orow0, ocol;
  if (lid < 768){
    seq = lid/384; int rem = lid - seq*384; h = rem>>5; qb = rem&31;
    Q=Qg; K=Kg; Vt=Vtg; L=2048;
    prow = pids + seq*512; orow0 = seq*2048; ocol = h*64;
  } else {
    int g2 = lid - 768; seq = g2/96; int rem = g2 - seq*96; h = rem>>3; qb = rem&7;
    Q=Qs; K=Ks; Vt=Vts; L=512;
    prow = pids + (seq&1)*512; orow0 = (seq&1)*2048 + (seq>>1)*512; ocol = 768 + h*64;
  }
  const size_t base = ((size_t)(seq*12) + h)*(size_t)L*64;
  const int q0 = qb*64, tq0 = q0 & 511;
  short8 qf[2];
  const int qrow = q0 + w*16 + (l&15);
  #pragma unroll
  for (int s=0;s<2;s++) qf[s] = *(const short8*)&Q[base + (size_t)qrow*64 + s*32 + (l>>4)*8];
  const int qlo = prow[tq0], qhi = prow[tq0+63];
  int sq[4];
  #pragma unroll
  for (int r=0;r<4;r++) sq[r] = prow[tq0 + w*16 + (l>>4)*4 + r];
  float mr[4], lsum[4]; f32x4 ao[4];
  #pragma unroll
  for (int r=0;r<4;r++){ mr[r]=-1e30f; lsum[r]=0.f; }
  #pragma unroll
  for (int d=0;d<4;d++){ f32x4 z={0.f,0.f,0.f,0.f}; ao[d]=z; }
  const int nk = L/64;
  for (int kt=0; kt<nk; ++kt){
    const int k0 = kt*64, tk0 = k0 & 511;
    const int klo = prow[tk0], khi = prow[tk0+63];
    if (khi < qlo || klo > qhi) continue;   // uniform skip (sorted segments)
    // ---- QK^T: K fragments straight from global
    f32x4 s4[4];
    #pragma unroll
    for (int kb=0;kb<4;kb++){
      const int krow = kb*16 + (l&15);
      f32x4 a = {0.f,0.f,0.f,0.f};
      #pragma unroll
      for (int s=0;s<2;s++){
        short8 kf = *(const short8*)&K[base + (size_t)(k0+krow)*64 + s*32 + (l>>4)*8];
        a = __builtin_amdgcn_mfma_f32_16x16x32_bf16(qf[s], kf, a, 0,0,0);
      }
      s4[kb] = a;
    }
    // ---- mask
    #pragma unroll
    for (int kb=0;kb<4;kb++){
      int sk = prow[tk0 + kb*16 + (l&15)];
      #pragma unroll
      for (int r=0;r<4;r++){
        float sv = s4[kb][r]*0.125f;
        s4[kb][r] = (sk == sq[r]) ? sv : -1e30f;
      }
    }
    // ---- online softmax
    float pv[4][4];
    #pragma unroll
    for (int r=0;r<4;r++){
      float mx = fmaxf(fmaxf(s4[0][r], s4[1][r]), fmaxf(s4[2][r], s4[3][r]));
      #pragma unroll
      for (int m=1;m<=8;m<<=1) mx = fmaxf(mx, __shfl_xor(mx, m, 64));
      float mn = fmaxf(mr[r], mx);
      float scale = __expf(mr[r]-mn);
      float psum = 0.f;
      #pragma unroll
      for (int kb=0;kb<4;kb++){
        float p = (s4[kb][r] > -1e29f) ? __expf(s4[kb][r]-mn) : 0.f;
        pv[kb][r] = p; psum += p;
      }
      #pragma unroll
      for (int m=1;m<=8;m<<=1) psum += __shfl_xor(psum, m, 64);
      lsum[r] = lsum[r]*scale + psum;
      mr[r] = mn;
      #pragma unroll
      for (int d=0;d<4;d++) ao[d][r] *= scale;
    }
    // ---- P fragment relayout via per-wave LDS (no barrier: wave-private slice)
    #pragma unroll
    for (int kb=0;kb<4;kb++)
      #pragma unroll
      for (int r=0;r<4;r++){
        int prw = (l>>4)*4 + r;
        Pl[w][prw*64 + (((kb*32 + (l&15)*2) ^ ((prw&7)<<4))>>1)] = f2bf(pv[kb][r]);
      }
    short8 pa[2];
    #pragma unroll
    for (int s=0;s<2;s++)
      pa[s] = *(const short8*)&Pl[w][(l&15)*64 + (((s*64 + (l>>4)*16) ^ (((l&15)&7)<<4))>>1)];
    // ---- PV: V^T fragments straight from global
    #pragma unroll
    for (int d=0;d<4;d++){
      const size_t vrow = base + (size_t)(d*16 + (l&15))*L + k0;
      #pragma unroll
      for (int s=0;s<2;s++){
        short8 vf = *(const short8*)&Vt[vrow + s*32 + (l>>4)*8];
        ao[d] = __builtin_amdgcn_mfma_f32_16x16x32_bf16(pa[s], vf, ao[d], 0,0,0);
      }
    }
  }
  #pragma unroll
  for (int d=0;d<4;d++){
    int col = ocol + d*16 + (l&15);
    #pragma unroll
    for (int r=0;r<4;r++){
      int row = orow0 + q0 + w*16 + (l>>4)*4 + r;
      Out[(size_t)row*1536 + col] = f2bf(ao[d][r] / lsum[r]);
    }
  }
}

extern "C" void kernel_launch(void* const* d_in, const int* in_sizes, int n_in,
                              void* d_out, int out_size, void* d_ws, size_t ws_size,
                              hipStream_t stream) {
  const float* x      = (const float*)d_in[0];
  const int*   patch  = (const int*)d_in[1];
  const float* sincos = (const float*)d_in[2];
  const float* ln1s   = (const float*)d_in[3];
  const float* wqkv   = (const float*)d_in[4];
  const float* aq     = (const float*)d_in[5];
  const float* ak     = (const float*)d_in[6];
  const float* aqs    = (const float*)d_in[7];
  const float* aks    = (const float*)d_in[8];
  const float* wout   = (const float*)d_in[9];
  const float* bout   = (const float*)d_in[10];
  const float* ls1    = (const float*)d_in[11];
  const float* ln2s   = (const float*)d_in[12];
  const float* ln2b   = (const float*)d_in[13];
  const float* wm1    = (const float*)d_in[14];
  const float* bm1    = (const float*)d_in[15];
  const float* wm2    = (const float*)d_in[16];
  const float* bm2    = (const float*)d_in[17];
  const float* ls2    = (const float*)d_in[18];
  float* out = (float*)d_out;

  char* ws = (char*)d_ws;
  size_t off = 0;
  auto alloc = [&](size_t bytes)->void*{ void* p = ws + off; off += (bytes + 255) & ~(size_t)255; return p; };
  u16*  wqkvT = (u16*)alloc(4608ull*768*2);
  u16*  woutT = (u16*)alloc(768ull*1536*2);
  u16*  wm1T  = (u16*)alloc(3072ull*768*2);
  u16*  wm2T  = (u16*)alloc(768ull*3072*2);
  u16*  xin   = (u16*)alloc(4096ull*768*2);
  u16*  qkvb  = (u16*)alloc(4096ull*4608*2);   // bf16 qkv; ALSO aliased by split-K partials P
  u16*  qg    = (u16*)alloc(3145728ull*2);     // (P spans qkvb+qg+kg = 50,331,648 B exactly)
  u16*  kg    = (u16*)alloc(3145728ull*2);
  u16*  vg    = (u16*)alloc(3145728ull*2);     // transposed [2][12][64][2048]
  u16*  qsg   = (u16*)alloc(3145728ull*2);
  u16*  ksg   = (u16*)alloc(3145728ull*2);
  u16*  vsg   = (u16*)alloc(3145728ull*2);     // transposed [8][12][64][512]
  u16*  cat   = (u16*)alloc(4096ull*1536*2);
  float* x0   = (float*)alloc(4096ull*768*4);
  u16*  x1    = (u16*)alloc(4096ull*768*2);
  u16*  hbuf  = (u16*)alloc(4096ull*3072*2);
  float* P    = (float*)qkvb;                  // 4 x 4096 x 768 f32 partial planes

  dim3 b256(256);
  wtrans_k<<<dim3(144,24),b256,0,stream>>>(wqkv, wqkvT, 768, 4608);
  wtrans_k<<<dim3(24,48),b256,0,stream>>>(wout, woutT, 1536, 768);
  wtrans_k<<<dim3(96,24),b256,0,stream>>>(wm1, wm1T, 768, 3072);
  wtrans_k<<<dim3(24,96),b256,0,stream>>>(wm2, wm2T, 3072, 768);
  ln1_k<<<4096,b256,0,stream>>>(x, ln1s, xin);
  gemm_k<3,1><<<dim3(36,32),b256,0,stream>>>(xin, wqkvT, 4096, 4608, 768, nullptr, qkvb, nullptr);
  postproc_k<<<4096,b256,0,stream>>>(qkvb, sincos, aq, ak, aqs, aks, qg,kg,vg,qsg,ksg,vsg);
  attn2_k<<<1536,b256,0,stream>>>(qg,kg,vg, qsg,ksg,vsg, cat, patch);
  gemm_k<0,4><<<dim3(6,32,4),b256,0,stream>>>(cat, woutT, 4096, 768, 1536, P, nullptr, nullptr);
  redln_k<<<4096,b256,0,stream>>>(P, bout, ls1, x, ln2s, ln2b, x0, x1);
  gemm_k<2,1><<<dim3(24,32),b256,0,stream>>>(x1, wm1T, 4096, 3072, 768, nullptr, hbuf, bm1);
  gemm_k<0,4><<<dim3(6,32,4),b256,0,stream>>>(hbuf, wm2T, 4096, 768, 3072, P, nullptr, nullptr);
  red_k<<<3072,b256,0,stream>>>(P, bm2, ls2, x0, out);
}

// Round 4
// 350.236 us; speedup vs baseline: 1.1202x; 1.1202x over previous
//
#include <hip/hip_runtime.h>

#define DEVI __device__ __forceinline__

typedef __attribute__((ext_vector_type(8))) short short8;
typedef __attribute__((ext_vector_type(4))) float f32x4;
typedef unsigned short u16;

DEVI u16 f2bf(float f){
  unsigned int u = __float_as_uint(f);
  unsigned int r = (u + 0x7FFFu + ((u>>16)&1u)) >> 16;
  return (u16)r;
}
DEVI float bf2f(u16 h){ return __uint_as_float(((unsigned int)h)<<16); }

DEVI float gelu_f(float x){
  float x3 = x*x*x;
  float t = tanhf(0.7978845608028654f*(x + 0.044715f*x3));
  return 0.5f*x*(1.0f + t);
}

DEVI void async_cp16(const void* g, void* l){
  __builtin_amdgcn_global_load_lds(
      (const __attribute__((address_space(1))) unsigned int*)g,
      (__attribute__((address_space(3))) unsigned int*)l, 16, 0, 0);
}

// ---------------- weight transpose + bf16 convert: w (K x N) f32 -> wt (N x K) bf16
__global__ __launch_bounds__(256) void wtrans_k(const float* __restrict__ w,
                                                u16* __restrict__ wt, int K, int N){
  __shared__ float tile[32][33];
  int tn = blockIdx.x*32, tk = blockIdx.y*32;
  int r = threadIdx.x>>3, c4 = (threadIdx.x&7)*4;
  float4 vv = *(const float4*)&w[(size_t)(tk+r)*N + tn + c4];
  tile[r][c4+0]=vv.x; tile[r][c4+1]=vv.y; tile[r][c4+2]=vv.z; tile[r][c4+3]=vv.w;
  __syncthreads();
  u16 o[4];
  #pragma unroll
  for (int j=0;j<4;j++) o[j] = f2bf(tile[c4+j][r]);
  unsigned long long pk = (unsigned long long)o[0] | ((unsigned long long)o[1]<<16)
                        | ((unsigned long long)o[2]<<32) | ((unsigned long long)o[3]<<48);
  *(unsigned long long*)&wt[(size_t)(tn+r)*K + tk + c4] = pk;
}

// ---------------- LN1: x f32 (4096x768) -> xin bf16
__global__ __launch_bounds__(256) void ln1_k(const float* __restrict__ x,
                                             const float* __restrict__ sc,
                                             u16* __restrict__ xin){
  int row = blockIdx.x, tid = threadIdx.x;
  const float* xr = x + (size_t)row*768;
  float v[3]; float s=0.f, ss=0.f;
  #pragma unroll
  for (int i=0;i<3;i++){ v[i]=xr[tid+i*256]; s+=v[i]; ss+=v[i]*v[i]; }
  #pragma unroll
  for (int m=1;m<=32;m<<=1){ s += __shfl_xor(s,m,64); ss += __shfl_xor(ss,m,64); }
  __shared__ float ls0[4], ls1_[4];
  int w = tid>>6;
  if ((tid&63)==0){ ls0[w]=s; ls1_[w]=ss; }
  __syncthreads();
  s = ls0[0]+ls0[1]+ls0[2]+ls0[3]; ss = ls1_[0]+ls1_[1]+ls1_[2]+ls1_[3];
  float mu = s*(1.f/768.f);
  float var = ss*(1.f/768.f) - mu*mu;
  float inv = rsqrtf(var + 1e-6f);
  #pragma unroll
  for (int i=0;i<3;i++){ int c=tid+i*256; xin[(size_t)row*768+c] = f2bf((v[i]-mu)*inv*sc[c]); }
}

// ---------------- GEMM: C(MxN) = A(MxK,bf16) * Bt(NxK,bf16)^T
// EPI 0: f32 partial plane (split-K)   EPI 2: bf16(gelu(acc+bias))   EPI 3: plain bf16
template<int EPI, int SPLITK>
__global__ __launch_bounds__(256) void gemm_k(
    const u16* __restrict__ A, const u16* __restrict__ Bt,
    int M, int N, int K,
    float* __restrict__ Cf, u16* __restrict__ Cb,
    const float* __restrict__ bias)
{
  __shared__ __align__(16) u16 Al[128*32];
  __shared__ __align__(16) u16 Bl[128*32];
  const int tid = threadIdx.x, w = tid>>6, l = tid&63;
  const int m0 = blockIdx.y*128, n0 = blockIdx.x*128;
  const int Ksub = K/SPLITK;
  const int kc = (SPLITK>1) ? blockIdx.z : 0;
  const int kbase = kc*Ksub;
  const int wr = (w>>1)*64, wc = (w&1)*64;
  f32x4 acc[4][4];
  #pragma unroll
  for (int i=0;i<4;i++)
    #pragma unroll
    for (int j=0;j<4;j++){ f32x4 z={0.f,0.f,0.f,0.f}; acc[i][j]=z; }
  const int lr = l>>2, lc = l&3;
  for (int k0=0; k0<Ksub; k0+=32){
    __syncthreads();
    #pragma unroll
    for (int it=0; it<2; ++it){
      int arow = w*32 + it*16;
      async_cp16(A  + (size_t)(m0+arow+lr)*K + kbase + k0 + lc*8, &Al[arow*32]);
      async_cp16(Bt + (size_t)(n0+arow+lr)*K + kbase + k0 + lc*8, &Bl[arow*32]);
    }
    __syncthreads();
    short8 af[4], bfr[4];
    #pragma unroll
    for (int mi=0;mi<4;++mi) af[mi]  = *(const short8*)&Al[(wr+mi*16+(l&15))*32 + (l>>4)*8];
    #pragma unroll
    for (int ni=0;ni<4;++ni) bfr[ni] = *(const short8*)&Bl[(wc+ni*16+(l&15))*32 + (l>>4)*8];
    #pragma unroll
    for (int mi=0;mi<4;++mi)
      #pragma unroll
      for (int ni=0;ni<4;++ni)
        acc[mi][ni] = __builtin_amdgcn_mfma_f32_16x16x32_bf16(af[mi], bfr[ni], acc[mi][ni], 0,0,0);
  }
  #pragma unroll
  for (int mi=0;mi<4;++mi){
    int rb = m0 + wr + mi*16 + ((l>>4)<<2);
    #pragma unroll
    for (int ni=0;ni<4;++ni){
      int col = n0 + wc + ni*16 + (l&15);
      #pragma unroll
      for (int r=0;r<4;r++){
        int row = rb + r;
        float v = acc[mi][ni][r];
        if (EPI==0)      Cf[((size_t)kc*M + row)*N + col] = v;
        else if (EPI==2) Cb[(size_t)row*N+col] = f2bf(gelu_f(v + bias[col]));
        else             Cb[(size_t)row*N+col] = f2bf(v);
      }
    }
  }
}

// ---------------- split-K reduce + bias/ls/resid + LN2 + gelu (out-proj path)
__global__ __launch_bounds__(256) void redln_k(
    const float* __restrict__ P, const float* __restrict__ bias,
    const float* __restrict__ lsc, const float* __restrict__ resid,
    const float* __restrict__ ln2sc, const float* __restrict__ ln2bi,
    float* __restrict__ x0, u16* __restrict__ x1)
{
  const size_t MN = 4096ull*768;
  int row = blockIdx.x, tid = threadIdx.x;
  float v[3]; float s=0.f, ss=0.f;
  #pragma unroll
  for (int i=0;i<3;i++){
    int c = tid + i*256;
    size_t idx = (size_t)row*768 + c;
    float acc = P[idx] + P[MN+idx] + P[2*MN+idx] + P[3*MN+idx];
    float y = lsc[c]*(acc + bias[c]) + resid[idx];
    x0[idx] = y;
    v[i] = y; s += y; ss += y*y;
  }
  #pragma unroll
  for (int m=1;m<=32;m<<=1){ s += __shfl_xor(s,m,64); ss += __shfl_xor(ss,m,64); }
  __shared__ float ls0[4], ls1_[4];
  int w = tid>>6;
  if ((tid&63)==0){ ls0[w]=s; ls1_[w]=ss; }
  __syncthreads();
  s = ls0[0]+ls0[1]+ls0[2]+ls0[3]; ss = ls1_[0]+ls1_[1]+ls1_[2]+ls1_[3];
  float mu = s*(1.f/768.f);
  float var = ss*(1.f/768.f) - mu*mu;
  float inv = rsqrtf(var + 1e-6f);
  #pragma unroll
  for (int i=0;i<3;i++){
    int c = tid + i*256;
    float y = (v[i]-mu)*inv*ln2sc[c] + ln2bi[c];
    x1[(size_t)row*768 + c] = f2bf(gelu_f(y));
  }
}

// ---------------- split-K reduce + bias/ls/resid (final output)
__global__ __launch_bounds__(256) void red_k(
    const float* __restrict__ P, const float* __restrict__ bias,
    const float* __restrict__ lsc, const float* __restrict__ resid,
    float* __restrict__ out)
{
  const size_t MN = 4096ull*768;
  size_t i = ((size_t)blockIdx.x*256 + threadIdx.x)*4;
  int c = (int)(i % 768);
  float4 a0 = *(const float4*)&P[i];
  float4 a1 = *(const float4*)&P[MN+i];
  float4 a2 = *(const float4*)&P[2*MN+i];
  float4 a3 = *(const float4*)&P[3*MN+i];
  float4 bi = *(const float4*)&bias[c];
  float4 ls = *(const float4*)&lsc[c];
  float4 rs = *(const float4*)&resid[i];
  float4 o;
  o.x = ls.x*(a0.x+a1.x+a2.x+a3.x + bi.x) + rs.x;
  o.y = ls.y*(a0.y+a1.y+a2.y+a3.y + bi.y) + rs.y;
  o.z = ls.z*(a0.z+a1.z+a2.z+a3.z + bi.z) + rs.z;
  o.w = ls.w*(a0.w+a1.w+a2.w+a3.w + bi.w) + rs.w;
  *(float4*)&out[i] = o;
}

// ---------------- qkv postprocess: rms + rope + layout split
// V tensors are written TRANSPOSED: [seq][h][d=64][L]
__global__ __launch_bounds__(256) void postproc_k(
  const u16* __restrict__ qkv, const float* __restrict__ sincos,
  const float* __restrict__ aq, const float* __restrict__ ak,
  const float* __restrict__ aqs, const float* __restrict__ aks,
  u16* __restrict__ qg, u16* __restrict__ kg, u16* __restrict__ vg,
  u16* __restrict__ qsg, u16* __restrict__ ksg, u16* __restrict__ vsg)
{
  int m = blockIdx.x;
  int b = m>>11, v = (m>>9)&3, t = m&511;
  int w = threadIdx.x>>6, l = threadIdx.x&63;
  for (int inst = w; inst < 72; inst += 4){
    int tt = inst/12, h = inst - tt*12;
    float val = bf2f(qkv[(size_t)m*4608 + tt*768 + h*64 + l]);
    size_t gidx = (((size_t)(b*12) + h)*2048 + v*512 + t)*64 + l;
    size_t sidx = (((size_t)((v*2+b)*12) + h)*512 + t)*64 + l;
    if (tt==2){ vg[(((size_t)(b*12) + h)*64 + l)*2048 + v*512 + t] = f2bf(val); continue; }
    if (tt==5){ vsg[(((size_t)((v*2+b)*12) + h)*64 + l)*512 + t] = f2bf(val); continue; }
    float ss = val*val;
    #pragma unroll
    for (int mm=1;mm<=32;mm<<=1) ss += __shfl_xor(ss,mm,64);
    float mag = sqrtf(ss*(1.f/64.f) + 1e-5f);
    const float* al = (tt==0)?aq:(tt==1)?ak:(tt==3)?aqs:aks;
    val = al[h*64+l]*val/mag;
    float cs = sincos[((size_t)t*64 + l)*2];
    float sn = sincos[((size_t)t*64 + l)*2 + 1];
    float partner = __shfl_xor(val, 1, 64);
    float rot = (l&1) ? partner : -partner;
    val = val*cs + rot*sn;
    u16 bv = f2bf(val);
    if (tt==0) qg[gidx] = bv;
    else if (tt==1) kg[gidx] = bv;
    else if (tt==3) qsg[sidx] = bv;
    else ksg[sidx] = bv;
  }
}

// ---------------- merged segment-masked flash attention (one launch)
// Q/K: [seq][h][L][64] bf16 ; Vt: [seq][h][64][L] bf16 ; Out bf16 [4096][1536]
// K/Vt tiles double-buffered in LDS (reg-staged, XOR-swizzled ds_write_b128);
// next tile's global loads issued before current tile's compute (T14).
// Active k-tiles precomputed as a bitmask (segments sorted) -> 1 barrier/tile.
__global__ __launch_bounds__(256) void attn3_k(
  const u16* __restrict__ Qg, const u16* __restrict__ Kg, const u16* __restrict__ Vtg,
  const u16* __restrict__ Qs, const u16* __restrict__ Ks, const u16* __restrict__ Vts,
  u16* __restrict__ Out, const int* __restrict__ pids)
{
  __shared__ __align__(16) u16 Kl[2][64*64];
  __shared__ __align__(16) u16 Vl[2][64*64];
  __shared__ __align__(16) u16 Pl[4][16*64];
  __shared__ unsigned long long amask_s;
  const int gid = blockIdx.x;
  const int lid = (gid & 7)*192 + (gid >> 3);   // XCD-chunked swizzle (1536 = 8*192)
  const int tid = threadIdx.x, w = tid>>6, l = tid&63;
  const u16 *Q, *K, *Vt; const int* prow;
  int L, seq, h, qb, orow0, ocol;
  if (lid < 768){
    seq = lid/384; int rem2 = lid - seq*384; h = rem2>>5; qb = rem2&31;
    Q=Qg; K=Kg; Vt=Vtg; L=2048;
    prow = pids + seq*512; orow0 = seq*2048; ocol = h*64;
  } else {
    int g2 = lid - 768; seq = g2/96; int rem2 = g2 - seq*96; h = rem2>>3; qb = rem2&7;
    Q=Qs; K=Ks; Vt=Vts; L=512;
    prow = pids + (seq&1)*512; orow0 = (seq&1)*2048 + (seq>>1)*512; ocol = 768 + h*64;
  }
  const size_t base = ((size_t)(seq*12) + h)*(size_t)L*64;
  const int q0 = qb*64, tq0 = q0 & 511;
  short8 qf[2];
  const int qrow = q0 + w*16 + (l&15);
  #pragma unroll
  for (int s=0;s<2;s++) qf[s] = *(const short8*)&Q[base + (size_t)qrow*64 + s*32 + (l>>4)*8];
  const int qlo = prow[tq0], qhi = prow[tq0+63];
  int sq[4];
  #pragma unroll
  for (int r=0;r<4;r++) sq[r] = prow[tq0 + w*16 + (l>>4)*4 + r];
  float mr[4], lsum[4]; f32x4 ao[4];
  #pragma unroll
  for (int r=0;r<4;r++){ mr[r]=-1e30f; lsum[r]=0.f; }
  #pragma unroll
  for (int d=0;d<4;d++){ f32x4 z={0.f,0.f,0.f,0.f}; ao[d]=z; }
  const int nk = L/64;
  // ---- active-tile bitmask (uniform): wave 0 ballots over segment ranges
  bool act = false;
  if (tid < 64 && tid < nk){
    int tk0 = (tid*64)&511;
    act = (prow[tk0+63] >= qlo) && (prow[tk0] <= qhi);
  }
  unsigned long long bm = __ballot(act);
  if (tid==0) amask_s = bm;
  __syncthreads();
  unsigned long long rem = amask_s;   // non-empty: diagonal tile always active
  int t = (int)(__ffsll((unsigned long long)rem)-1); rem &= rem-1;
  uint4 kr[2], vr[2];
  {  // prologue: stage first tile
    int k0 = t*64;
    #pragma unroll
    for (int it=0;it<2;++it){
      int slot=it*256+tid, row=slot>>3, c16=slot&7;
      kr[it] = *(const uint4*)&K[base + (size_t)(k0+row)*64 + c16*8];
      vr[it] = *(const uint4*)&Vt[base + (size_t)row*(size_t)L + k0 + c16*8];
    }
    #pragma unroll
    for (int it=0;it<2;++it){
      int slot=it*256+tid, row=slot>>3, c16=slot&7;
      int boff = row*128 + ((c16*16) ^ ((row&7)<<4));
      *(uint4*)((char*)&Kl[0][0] + boff) = kr[it];
      *(uint4*)((char*)&Vl[0][0] + boff) = vr[it];
    }
  }
  __syncthreads();
  int cur = 0;
  while (true){
    int tn = rem ? (int)(__ffsll((unsigned long long)rem)-1) : -1;
    if (tn >= 0){           // issue next tile's loads now; they land during compute
      rem &= rem-1;
      int k0n = tn*64;
      #pragma unroll
      for (int it=0;it<2;++it){
        int slot=it*256+tid, row=slot>>3, c16=slot&7;
        kr[it] = *(const uint4*)&K[base + (size_t)(k0n+row)*64 + c16*8];
        vr[it] = *(const uint4*)&Vt[base + (size_t)row*(size_t)L + k0n + c16*8];
      }
    }
    // ---- compute current tile from LDS
    const int tk0 = (t*64) & 511;
    const u16* Kb = &Kl[cur][0];
    const u16* Vb = &Vl[cur][0];
    f32x4 s4[4];
    #pragma unroll
    for (int kb=0;kb<4;kb++){
      const int krow = kb*16 + (l&15);
      f32x4 a = {0.f,0.f,0.f,0.f};
      #pragma unroll
      for (int s=0;s<2;s++){
        int boff = krow*128 + ((s*64 + (l>>4)*16) ^ ((krow&7)<<4));
        short8 kf = *(const short8*)((const char*)Kb + boff);
        a = __builtin_amdgcn_mfma_f32_16x16x32_bf16(qf[s], kf, a, 0,0,0);
      }
      s4[kb] = a;
    }
    #pragma unroll
    for (int kb=0;kb<4;kb++){
      int sk = prow[tk0 + kb*16 + (l&15)];
      #pragma unroll
      for (int r=0;r<4;r++){
        float sv = s4[kb][r]*0.125f;
        s4[kb][r] = (sk == sq[r]) ? sv : -1e30f;
      }
    }
    float pv[4][4];
    #pragma unroll
    for (int r=0;r<4;r++){
      float mx = fmaxf(fmaxf(s4[0][r], s4[1][r]), fmaxf(s4[2][r], s4[3][r]));
      #pragma unroll
      for (int m=1;m<=8;m<<=1) mx = fmaxf(mx, __shfl_xor(mx, m, 64));
      float mn = fmaxf(mr[r], mx);
      float scale = __expf(mr[r]-mn);
      float psum = 0.f;
      #pragma unroll
      for (int kb=0;kb<4;kb++){
        float p = (s4[kb][r] > -1e29f) ? __expf(s4[kb][r]-mn) : 0.f;
        pv[kb][r] = p; psum += p;
      }
      #pragma unroll
      for (int m=1;m<=8;m<<=1) psum += __shfl_xor(psum, m, 64);
      lsum[r] = lsum[r]*scale + psum;
      mr[r] = mn;
      #pragma unroll
      for (int d=0;d<4;d++) ao[d][r] *= scale;
    }
    #pragma unroll
    for (int kb=0;kb<4;kb++)
      #pragma unroll
      for (int r=0;r<4;r++){
        int prw = (l>>4)*4 + r;
        Pl[w][prw*64 + (((kb*32 + (l&15)*2) ^ ((prw&7)<<4))>>1)] = f2bf(pv[kb][r]);
      }
    short8 pa[2];
    #pragma unroll
    for (int s=0;s<2;s++)
      pa[s] = *(const short8*)&Pl[w][(l&15)*64 + (((s*64 + (l>>4)*16) ^ (((l&15)&7)<<4))>>1)];
    #pragma unroll
    for (int d=0;d<4;d++){
      const int vrow = d*16 + (l&15);
      #pragma unroll
      for (int s=0;s<2;s++){
        int boff = vrow*128 + ((s*64 + (l>>4)*16) ^ ((vrow&7)<<4));
        short8 vf = *(const short8*)((const char*)Vb + boff);
        ao[d] = __builtin_amdgcn_mfma_f32_16x16x32_bf16(pa[s], vf, ao[d], 0,0,0);
      }
    }
    if (tn < 0) break;
    // ---- stage next tile into the other buffer (safe: it was last read 1 iter
    // ago, and the barrier below in that iteration ordered all waves past it)
    #pragma unroll
    for (int it=0;it<2;++it){
      int slot=it*256+tid, row=slot>>3, c16=slot&7;
      int boff = row*128 + ((c16*16) ^ ((row&7)<<4));
      *(uint4*)((char*)&Kl[cur^1][0] + boff) = kr[it];
      *(uint4*)((char*)&Vl[cur^1][0] + boff) = vr[it];
    }
    __syncthreads();
    cur ^= 1; t = tn;
  }
  #pragma unroll
  for (int d=0;d<4;d++){
    int col = ocol + d*16 + (l&15);
    #pragma unroll
    for (int r=0;r<4;r++){
      int row = orow0 + q0 + w*16 + (l>>4)*4 + r;
      Out[(size_t)row*1536 + col] = f2bf(ao[d][r] / lsum[r]);
    }
  }
}

extern "C" void kernel_launch(void* const* d_in, const int* in_sizes, int n_in,
                              void* d_out, int out_size, void* d_ws, size_t ws_size,
                              hipStream_t stream) {
  const float* x      = (const float*)d_in[0];
  const int*   patch  = (const int*)d_in[1];
  const float* sincos = (const float*)d_in[2];
  const float* ln1s   = (const float*)d_in[3];
  const float* wqkv   = (const float*)d_in[4];
  const float* aq     = (const float*)d_in[5];
  const float* ak     = (const float*)d_in[6];
  const float* aqs    = (const float*)d_in[7];
  const float* aks    = (const float*)d_in[8];
  const float* wout   = (const float*)d_in[9];
  const float* bout   = (const float*)d_in[10];
  const float* ls1    = (const float*)d_in[11];
  const float* ln2s   = (const float*)d_in[12];
  const float* ln2b   = (const float*)d_in[13];
  const float* wm1    = (const float*)d_in[14];
  const float* bm1    = (const float*)d_in[15];
  const float* wm2    = (const float*)d_in[16];
  const float* bm2    = (const float*)d_in[17];
  const float* ls2    = (const float*)d_in[18];
  float* out = (float*)d_out;

  char* ws = (char*)d_ws;
  size_t off = 0;
  auto alloc = [&](size_t bytes)->void*{ void* p = ws + off; off += (bytes + 255) & ~(size_t)255; return p; };
  u16*  wqkvT = (u16*)alloc(4608ull*768*2);
  u16*  woutT = (u16*)alloc(768ull*1536*2);
  u16*  wm1T  = (u16*)alloc(3072ull*768*2);
  u16*  wm2T  = (u16*)alloc(768ull*3072*2);
  u16*  xin   = (u16*)alloc(4096ull*768*2);
  u16*  qkvb  = (u16*)alloc(4096ull*4608*2);   // bf16 qkv; ALSO aliased by split-K partials P
  u16*  qg    = (u16*)alloc(3145728ull*2);     // (P spans qkvb+qg+kg = 50,331,648 B exactly)
  u16*  kg    = (u16*)alloc(3145728ull*2);
  u16*  vg    = (u16*)alloc(3145728ull*2);     // transposed [2][12][64][2048]
  u16*  qsg   = (u16*)alloc(3145728ull*2);
  u16*  ksg   = (u16*)alloc(3145728ull*2);
  u16*  vsg   = (u16*)alloc(3145728ull*2);     // transposed [8][12][64][512]
  u16*  cat   = (u16*)alloc(4096ull*1536*2);
  float* x0   = (float*)alloc(4096ull*768*4);
  u16*  x1    = (u16*)alloc(4096ull*768*2);
  u16*  hbuf  = (u16*)alloc(4096ull*3072*2);
  float* P    = (float*)qkvb;                  // 4 x 4096 x 768 f32 partial planes

  dim3 b256(256);
  wtrans_k<<<dim3(144,24),b256,0,stream>>>(wqkv, wqkvT, 768, 4608);
  wtrans_k<<<dim3(24,48),b256,0,stream>>>(wout, woutT, 1536, 768);
  wtrans_k<<<dim3(96,24),b256,0,stream>>>(wm1, wm1T, 768, 3072);
  wtrans_k<<<dim3(24,96),b256,0,stream>>>(wm2, wm2T, 3072, 768);
  ln1_k<<<4096,b256,0,stream>>>(x, ln1s, xin);
  gemm_k<3,1><<<dim3(36,32),b256,0,stream>>>(xin, wqkvT, 4096, 4608, 768, nullptr, qkvb, nullptr);
  postproc_k<<<4096,b256,0,stream>>>(qkvb, sincos, aq, ak, aqs, aks, qg,kg,vg,qsg,ksg,vsg);
  attn3_k<<<1536,b256,0,stream>>>(qg,kg,vg, qsg,ksg,vsg, cat, patch);
  gemm_k<0,4><<<dim3(6,32,4),b256,0,stream>>>(cat, woutT, 4096, 768, 1536, P, nullptr, nullptr);
  redln_k<<<4096,b256,0,stream>>>(P, bout, ls1, x, ln2s, ln2b, x0, x1);
  gemm_k<2,1><<<dim3(24,32),b256,0,stream>>>(x1, wm1T, 4096, 3072, 768, nullptr, hbuf, bm1);
  gemm_k<0,4><<<dim3(6,32,4),b256,0,stream>>>(hbuf, wm2T, 4096, 768, 3072, P, nullptr, nullptr);
  red_k<<<3072,b256,0,stream>>>(P, bm2, ls2, x0, out);
}

// Round 5
// 311.004 us; speedup vs baseline: 1.2615x; 1.1261x over previous
//
#include <hip/hip_runtime.h>

#define DEVI __device__ __forceinline__

typedef __attribute__((ext_vector_type(8))) short short8;
typedef __attribute__((ext_vector_type(4))) float f32x4;
typedef unsigned short u16;

DEVI u16 f2bf(float f){
  unsigned int u = __float_as_uint(f);
  unsigned int r = (u + 0x7FFFu + ((u>>16)&1u)) >> 16;
  return (u16)r;
}
DEVI float bf2f(u16 h){ return __uint_as_float(((unsigned int)h)<<16); }

DEVI float gelu_f(float x){
  float x3 = x*x*x;
  float t = tanhf(0.7978845608028654f*(x + 0.044715f*x3));
  return 0.5f*x*(1.0f + t);
}

DEVI void async_cp16(const void* g, void* l){
  __builtin_amdgcn_global_load_lds(
      (const __attribute__((address_space(1))) unsigned int*)g,
      (__attribute__((address_space(3))) unsigned int*)l, 16, 0, 0);
}

// ---------------- weight transpose + bf16 convert: w (K x N) f32 -> wt (N x K) bf16
__global__ __launch_bounds__(256) void wtrans_k(const float* __restrict__ w,
                                                u16* __restrict__ wt, int K, int N){
  __shared__ float tile[32][33];
  int tn = blockIdx.x*32, tk = blockIdx.y*32;
  int r = threadIdx.x>>3, c4 = (threadIdx.x&7)*4;
  float4 vv = *(const float4*)&w[(size_t)(tk+r)*N + tn + c4];
  tile[r][c4+0]=vv.x; tile[r][c4+1]=vv.y; tile[r][c4+2]=vv.z; tile[r][c4+3]=vv.w;
  __syncthreads();
  u16 o[4];
  #pragma unroll
  for (int j=0;j<4;j++) o[j] = f2bf(tile[c4+j][r]);
  unsigned long long pk = (unsigned long long)o[0] | ((unsigned long long)o[1]<<16)
                        | ((unsigned long long)o[2]<<32) | ((unsigned long long)o[3]<<48);
  *(unsigned long long*)&wt[(size_t)(tn+r)*K + tk + c4] = pk;
}

// ---------------- LN1: x f32 (4096x768) -> xin bf16
__global__ __launch_bounds__(256) void ln1_k(const float* __restrict__ x,
                                             const float* __restrict__ sc,
                                             u16* __restrict__ xin){
  int row = blockIdx.x, tid = threadIdx.x;
  const float* xr = x + (size_t)row*768;
  float v[3]; float s=0.f, ss=0.f;
  #pragma unroll
  for (int i=0;i<3;i++){ v[i]=xr[tid+i*256]; s+=v[i]; ss+=v[i]*v[i]; }
  #pragma unroll
  for (int m=1;m<=32;m<<=1){ s += __shfl_xor(s,m,64); ss += __shfl_xor(ss,m,64); }
  __shared__ float ls0[4], ls1_[4];
  int w = tid>>6;
  if ((tid&63)==0){ ls0[w]=s; ls1_[w]=ss; }
  __syncthreads();
  s = ls0[0]+ls0[1]+ls0[2]+ls0[3]; ss = ls1_[0]+ls1_[1]+ls1_[2]+ls1_[3];
  float mu = s*(1.f/768.f);
  float var = ss*(1.f/768.f) - mu*mu;
  float inv = rsqrtf(var + 1e-6f);
  #pragma unroll
  for (int i=0;i<3;i++){ int c=tid+i*256; xin[(size_t)row*768+c] = f2bf((v[i]-mu)*inv*sc[c]); }
}

// ---------------- GEMM: C(MxN) = A(MxK,bf16) * Bt(NxK,bf16)^T
// EPI 0: f32 partial plane (split-K)   EPI 2: bf16(gelu(acc+bias))   EPI 3: plain bf16
template<int EPI, int SPLITK>
__global__ __launch_bounds__(256) void gemm_k(
    const u16* __restrict__ A, const u16* __restrict__ Bt,
    int M, int N, int K,
    float* __restrict__ Cf, u16* __restrict__ Cb,
    const float* __restrict__ bias)
{
  __shared__ __align__(16) u16 Al[128*32];
  __shared__ __align__(16) u16 Bl[128*32];
  const int tid = threadIdx.x, w = tid>>6, l = tid&63;
  const int m0 = blockIdx.y*128, n0 = blockIdx.x*128;
  const int Ksub = K/SPLITK;
  const int kc = (SPLITK>1) ? blockIdx.z : 0;
  const int kbase = kc*Ksub;
  const int wr = (w>>1)*64, wc = (w&1)*64;
  f32x4 acc[4][4];
  #pragma unroll
  for (int i=0;i<4;i++)
    #pragma unroll
    for (int j=0;j<4;j++){ f32x4 z={0.f,0.f,0.f,0.f}; acc[i][j]=z; }
  const int lr = l>>2, lc = l&3;
  for (int k0=0; k0<Ksub; k0+=32){
    __syncthreads();
    #pragma unroll
    for (int it=0; it<2; ++it){
      int arow = w*32 + it*16;
      async_cp16(A  + (size_t)(m0+arow+lr)*K + kbase + k0 + lc*8, &Al[arow*32]);
      async_cp16(Bt + (size_t)(n0+arow+lr)*K + kbase + k0 + lc*8, &Bl[arow*32]);
    }
    __syncthreads();
    short8 af[4], bfr[4];
    #pragma unroll
    for (int mi=0;mi<4;++mi) af[mi]  = *(const short8*)&Al[(wr+mi*16+(l&15))*32 + (l>>4)*8];
    #pragma unroll
    for (int ni=0;ni<4;++ni) bfr[ni] = *(const short8*)&Bl[(wc+ni*16+(l&15))*32 + (l>>4)*8];
    #pragma unroll
    for (int mi=0;mi<4;++mi)
      #pragma unroll
      for (int ni=0;ni<4;++ni)
        acc[mi][ni] = __builtin_amdgcn_mfma_f32_16x16x32_bf16(af[mi], bfr[ni], acc[mi][ni], 0,0,0);
  }
  #pragma unroll
  for (int mi=0;mi<4;++mi){
    int rb = m0 + wr + mi*16 + ((l>>4)<<2);
    #pragma unroll
    for (int ni=0;ni<4;++ni){
      int col = n0 + wc + ni*16 + (l&15);
      #pragma unroll
      for (int r=0;r<4;r++){
        int row = rb + r;
        float v = acc[mi][ni][r];
        if (EPI==0)      Cf[((size_t)kc*M + row)*N + col] = v;
        else if (EPI==2) Cb[(size_t)row*N+col] = f2bf(gelu_f(v + bias[col]));
        else             Cb[(size_t)row*N+col] = f2bf(v);
      }
    }
  }
}

// ---------------- split-K reduce + bias/ls/resid + LN2 + gelu (out-proj path)
__global__ __launch_bounds__(256) void redln_k(
    const float* __restrict__ P, const float* __restrict__ bias,
    const float* __restrict__ lsc, const float* __restrict__ resid,
    const float* __restrict__ ln2sc, const float* __restrict__ ln2bi,
    float* __restrict__ x0, u16* __restrict__ x1)
{
  const size_t MN = 4096ull*768;
  int row = blockIdx.x, tid = threadIdx.x;
  float v[3]; float s=0.f, ss=0.f;
  #pragma unroll
  for (int i=0;i<3;i++){
    int c = tid + i*256;
    size_t idx = (size_t)row*768 + c;
    float acc = P[idx] + P[MN+idx] + P[2*MN+idx] + P[3*MN+idx];
    float y = lsc[c]*(acc + bias[c]) + resid[idx];
    x0[idx] = y;
    v[i] = y; s += y; ss += y*y;
  }
  #pragma unroll
  for (int m=1;m<=32;m<<=1){ s += __shfl_xor(s,m,64); ss += __shfl_xor(ss,m,64); }
  __shared__ float ls0[4], ls1_[4];
  int w = tid>>6;
  if ((tid&63)==0){ ls0[w]=s; ls1_[w]=ss; }
  __syncthreads();
  s = ls0[0]+ls0[1]+ls0[2]+ls0[3]; ss = ls1_[0]+ls1_[1]+ls1_[2]+ls1_[3];
  float mu = s*(1.f/768.f);
  float var = ss*(1.f/768.f) - mu*mu;
  float inv = rsqrtf(var + 1e-6f);
  #pragma unroll
  for (int i=0;i<3;i++){
    int c = tid + i*256;
    float y = (v[i]-mu)*inv*ln2sc[c] + ln2bi[c];
    x1[(size_t)row*768 + c] = f2bf(gelu_f(y));
  }
}

// ---------------- split-K reduce + bias/ls/resid (final output)
__global__ __launch_bounds__(256) void red_k(
    const float* __restrict__ P, const float* __restrict__ bias,
    const float* __restrict__ lsc, const float* __restrict__ resid,
    float* __restrict__ out)
{
  const size_t MN = 4096ull*768;
  size_t i = ((size_t)blockIdx.x*256 + threadIdx.x)*4;
  int c = (int)(i % 768);
  float4 a0 = *(const float4*)&P[i];
  float4 a1 = *(const float4*)&P[MN+i];
  float4 a2 = *(const float4*)&P[2*MN+i];
  float4 a3 = *(const float4*)&P[3*MN+i];
  float4 bi = *(const float4*)&bias[c];
  float4 ls = *(const float4*)&lsc[c];
  float4 rs = *(const float4*)&resid[i];
  float4 o;
  o.x = ls.x*(a0.x+a1.x+a2.x+a3.x + bi.x) + rs.x;
  o.y = ls.y*(a0.y+a1.y+a2.y+a3.y + bi.y) + rs.y;
  o.z = ls.z*(a0.z+a1.z+a2.z+a3.z + bi.z) + rs.z;
  o.w = ls.w*(a0.w+a1.w+a2.w+a3.w + bi.w) + rs.w;
  *(float4*)&out[i] = o;
}

// ---------------- qkv postprocess: rms + rope + layout split
// V tensors are written TRANSPOSED: [seq][h][d=64][L]
__global__ __launch_bounds__(256) void postproc_k(
  const u16* __restrict__ qkv, const float* __restrict__ sincos,
  const float* __restrict__ aq, const float* __restrict__ ak,
  const float* __restrict__ aqs, const float* __restrict__ aks,
  u16* __restrict__ qg, u16* __restrict__ kg, u16* __restrict__ vg,
  u16* __restrict__ qsg, u16* __restrict__ ksg, u16* __restrict__ vsg)
{
  int m = blockIdx.x;
  int b = m>>11, v = (m>>9)&3, t = m&511;
  int w = threadIdx.x>>6, l = threadIdx.x&63;
  for (int inst = w; inst < 72; inst += 4){
    int tt = inst/12, h = inst - tt*12;
    float val = bf2f(qkv[(size_t)m*4608 + tt*768 + h*64 + l]);
    size_t gidx = (((size_t)(b*12) + h)*2048 + v*512 + t)*64 + l;
    size_t sidx = (((size_t)((v*2+b)*12) + h)*512 + t)*64 + l;
    if (tt==2){ vg[(((size_t)(b*12) + h)*64 + l)*2048 + v*512 + t] = f2bf(val); continue; }
    if (tt==5){ vsg[(((size_t)((v*2+b)*12) + h)*64 + l)*512 + t] = f2bf(val); continue; }
    float ss = val*val;
    #pragma unroll
    for (int mm=1;mm<=32;mm<<=1) ss += __shfl_xor(ss,mm,64);
    float mag = sqrtf(ss*(1.f/64.f) + 1e-5f);
    const float* al = (tt==0)?aq:(tt==1)?ak:(tt==3)?aqs:aks;
    val = al[h*64+l]*val/mag;
    float cs = sincos[((size_t)t*64 + l)*2];
    float sn = sincos[((size_t)t*64 + l)*2 + 1];
    float partner = __shfl_xor(val, 1, 64);
    float rot = (l&1) ? partner : -partner;
    val = val*cs + rot*sn;
    u16 bv = f2bf(val);
    if (tt==0) qg[gidx] = bv;
    else if (tt==1) kg[gidx] = bv;
    else if (tt==3) qsg[sidx] = bv;
    else ksg[sidx] = bv;
  }
}

// ---------------- merged segment-masked flash attention (one launch)
// Q/K: [seq][h][L][64] bf16 ; Vt: [seq][h][64][L] bf16 ; Out bf16 [4096][1536]
// NO online max: scores provably bounded (|s|<=8 from rms-norm'd q,k), so
// p = exp(s) directly -> no rescale, per-lane lsum reduced once at the end.
// K/Vt double-buffered in LDS, reg-staged prefetch (T14), 1 barrier/tile.
__global__ __launch_bounds__(256) void attn4_k(
  const u16* __restrict__ Qg, const u16* __restrict__ Kg, const u16* __restrict__ Vtg,
  const u16* __restrict__ Qs, const u16* __restrict__ Ks, const u16* __restrict__ Vts,
  u16* __restrict__ Out, const int* __restrict__ pids)
{
  __shared__ __align__(16) u16 Kl[2][64*64];
  __shared__ __align__(16) u16 Vl[2][64*64];
  __shared__ __align__(16) u16 Pl[4][16*64];
  __shared__ unsigned long long amask_s;
  const int gid = blockIdx.x;
  // balanced XCD swizzle: each XCD gets 96 global + 96 shifted contiguous blocks
  const int xcd = gid & 7, idx = gid >> 3;
  const int lid = (idx < 96) ? xcd*96 + idx : 768 + xcd*96 + (idx - 96);
  const int tid = threadIdx.x, w = tid>>6, l = tid&63;
  const u16 *Q, *K, *Vt; const int* prow;
  int L, seq, h, qb, orow0, ocol;
  if (lid < 768){
    seq = lid/384; int rem2 = lid - seq*384; h = rem2>>5; qb = rem2&31;
    Q=Qg; K=Kg; Vt=Vtg; L=2048;
    prow = pids + seq*512; orow0 = seq*2048; ocol = h*64;
  } else {
    int g2 = lid - 768; seq = g2/96; int rem2 = g2 - seq*96; h = rem2>>3; qb = rem2&7;
    Q=Qs; K=Ks; Vt=Vts; L=512;
    prow = pids + (seq&1)*512; orow0 = (seq&1)*2048 + (seq>>1)*512; ocol = 768 + h*64;
  }
  const size_t base = ((size_t)(seq*12) + h)*(size_t)L*64;
  const int q0 = qb*64, tq0 = q0 & 511;
  short8 qf[2];
  const int qrow = q0 + w*16 + (l&15);
  #pragma unroll
  for (int s=0;s<2;s++) qf[s] = *(const short8*)&Q[base + (size_t)qrow*64 + s*32 + (l>>4)*8];
  const int qlo = prow[tq0], qhi = prow[tq0+63];
  int sq[4];
  #pragma unroll
  for (int r=0;r<4;r++) sq[r] = prow[tq0 + w*16 + (l>>4)*4 + r];
  float lsum[4]; f32x4 ao[4];
  #pragma unroll
  for (int r=0;r<4;r++) lsum[r]=0.f;
  #pragma unroll
  for (int d=0;d<4;d++){ f32x4 z={0.f,0.f,0.f,0.f}; ao[d]=z; }
  const int nk = L/64;
  // ---- active-tile bitmask (uniform): wave 0 ballots over segment ranges
  bool act = false;
  if (tid < 64 && tid < nk){
    int tk0 = (tid*64)&511;
    act = (prow[tk0+63] >= qlo) && (prow[tk0] <= qhi);
  }
  unsigned long long bm = __ballot(act);
  if (tid==0) amask_s = bm;
  __syncthreads();
  unsigned long long rem = amask_s;   // non-empty: diagonal tile always active
  int t = (int)(__ffsll((unsigned long long)rem)-1); rem &= rem-1;
  uint4 kr[2], vr[2];
  {  // prologue: stage first tile
    int k0 = t*64;
    #pragma unroll
    for (int it=0;it<2;++it){
      int slot=it*256+tid, row=slot>>3, c16=slot&7;
      kr[it] = *(const uint4*)&K[base + (size_t)(k0+row)*64 + c16*8];
      vr[it] = *(const uint4*)&Vt[base + (size_t)row*(size_t)L + k0 + c16*8];
    }
    #pragma unroll
    for (int it=0;it<2;++it){
      int slot=it*256+tid, row=slot>>3, c16=slot&7;
      int boff = row*128 + ((c16*16) ^ ((row&7)<<4));
      *(uint4*)((char*)&Kl[0][0] + boff) = kr[it];
      *(uint4*)((char*)&Vl[0][0] + boff) = vr[it];
    }
  }
  __syncthreads();
  int cur = 0;
  while (true){
    int tn = rem ? (int)(__ffsll((unsigned long long)rem)-1) : -1;
    if (tn >= 0){           // issue next tile's loads now; they land during compute
      rem &= rem-1;
      int k0n = tn*64;
      #pragma unroll
      for (int it=0;it<2;++it){
        int slot=it*256+tid, row=slot>>3, c16=slot&7;
        kr[it] = *(const uint4*)&K[base + (size_t)(k0n+row)*64 + c16*8];
        vr[it] = *(const uint4*)&Vt[base + (size_t)row*(size_t)L + k0n + c16*8];
      }
    }
    // ---- compute current tile from LDS
    const int tk0 = (t*64) & 511;
    const u16* Kb = &Kl[cur][0];
    const u16* Vb = &Vl[cur][0];
    f32x4 s4[4];
    #pragma unroll
    for (int kb=0;kb<4;kb++){
      const int krow = kb*16 + (l&15);
      f32x4 a = {0.f,0.f,0.f,0.f};
      #pragma unroll
      for (int s=0;s<2;s++){
        int boff = krow*128 + ((s*64 + (l>>4)*16) ^ ((krow&7)<<4));
        short8 kf = *(const short8*)((const char*)Kb + boff);
        a = __builtin_amdgcn_mfma_f32_16x16x32_bf16(qf[s], kf, a, 0,0,0);
      }
      s4[kb] = a;
    }
    // ---- mask + direct exp (no max subtraction: |s*0.125| <= 8)
    float pv[4][4];
    #pragma unroll
    for (int kb=0;kb<4;kb++){
      int sk = prow[tk0 + kb*16 + (l&15)];
      #pragma unroll
      for (int r=0;r<4;r++){
        float p = (sk == sq[r]) ? __expf(s4[kb][r]*0.125f) : 0.f;
        pv[kb][r] = p;
        lsum[r] += p;          // per-lane partial; reduced once at the end
      }
    }
    // ---- P fragment relayout via per-wave LDS (no barrier: wave-private slice)
    #pragma unroll
    for (int kb=0;kb<4;kb++)
      #pragma unroll
      for (int r=0;r<4;r++){
        int prw = (l>>4)*4 + r;
        Pl[w][prw*64 + (((kb*32 + (l&15)*2) ^ ((prw&7)<<4))>>1)] = f2bf(pv[kb][r]);
      }
    short8 pa[2];
    #pragma unroll
    for (int s=0;s<2;s++)
      pa[s] = *(const short8*)&Pl[w][(l&15)*64 + (((s*64 + (l>>4)*16) ^ (((l&15)&7)<<4))>>1)];
    #pragma unroll
    for (int d=0;d<4;d++){
      const int vrow = d*16 + (l&15);
      #pragma unroll
      for (int s=0;s<2;s++){
        int boff = vrow*128 + ((s*64 + (l>>4)*16) ^ ((vrow&7)<<4));
        short8 vf = *(const short8*)((const char*)Vb + boff);
        ao[d] = __builtin_amdgcn_mfma_f32_16x16x32_bf16(pa[s], vf, ao[d], 0,0,0);
      }
    }
    if (tn < 0) break;
    // ---- stage next tile into the other buffer
    #pragma unroll
    for (int it=0;it<2;++it){
      int slot=it*256+tid, row=slot>>3, c16=slot&7;
      int boff = row*128 + ((c16*16) ^ ((row&7)<<4));
      *(uint4*)((char*)&Kl[cur^1][0] + boff) = kr[it];
      *(uint4*)((char*)&Vl[cur^1][0] + boff) = vr[it];
    }
    __syncthreads();
    cur ^= 1; t = tn;
  }
  // ---- final row-sum reduce (16 lanes share a row-group)
  #pragma unroll
  for (int r=0;r<4;r++){
    #pragma unroll
    for (int m=1;m<=8;m<<=1) lsum[r] += __shfl_xor(lsum[r], m, 64);
  }
  #pragma unroll
  for (int d=0;d<4;d++){
    int col = ocol + d*16 + (l&15);
    #pragma unroll
    for (int r=0;r<4;r++){
      int row = orow0 + q0 + w*16 + (l>>4)*4 + r;
      Out[(size_t)row*1536 + col] = f2bf(ao[d][r] / lsum[r]);
    }
  }
}

extern "C" void kernel_launch(void* const* d_in, const int* in_sizes, int n_in,
                              void* d_out, int out_size, void* d_ws, size_t ws_size,
                              hipStream_t stream) {
  const float* x      = (const float*)d_in[0];
  const int*   patch  = (const int*)d_in[1];
  const float* sincos = (const float*)d_in[2];
  const float* ln1s   = (const float*)d_in[3];
  const float* wqkv   = (const float*)d_in[4];
  const float* aq     = (const float*)d_in[5];
  const float* ak     = (const float*)d_in[6];
  const float* aqs    = (const float*)d_in[7];
  const float* aks    = (const float*)d_in[8];
  const float* wout   = (const float*)d_in[9];
  const float* bout   = (const float*)d_in[10];
  const float* ls1    = (const float*)d_in[11];
  const float* ln2s   = (const float*)d_in[12];
  const float* ln2b   = (const float*)d_in[13];
  const float* wm1    = (const float*)d_in[14];
  const float* bm1    = (const float*)d_in[15];
  const float* wm2    = (const float*)d_in[16];
  const float* bm2    = (const float*)d_in[17];
  const float* ls2    = (const float*)d_in[18];
  float* out = (float*)d_out;

  char* ws = (char*)d_ws;
  size_t off = 0;
  auto alloc = [&](size_t bytes)->void*{ void* p = ws + off; off += (bytes + 255) & ~(size_t)255; return p; };
  u16*  wqkvT = (u16*)alloc(4608ull*768*2);
  u16*  woutT = (u16*)alloc(768ull*1536*2);
  u16*  wm1T  = (u16*)alloc(3072ull*768*2);
  u16*  wm2T  = (u16*)alloc(768ull*3072*2);
  u16*  xin   = (u16*)alloc(4096ull*768*2);
  u16*  qkvb  = (u16*)alloc(4096ull*4608*2);   // bf16 qkv; ALSO aliased by split-K partials P
  u16*  qg    = (u16*)alloc(3145728ull*2);     // (P spans qkvb+qg+kg = 50,331,648 B exactly)
  u16*  kg    = (u16*)alloc(3145728ull*2);
  u16*  vg    = (u16*)alloc(3145728ull*2);     // transposed [2][12][64][2048]
  u16*  qsg   = (u16*)alloc(3145728ull*2);
  u16*  ksg   = (u16*)alloc(3145728ull*2);
  u16*  vsg   = (u16*)alloc(3145728ull*2);     // transposed [8][12][64][512]
  u16*  cat   = (u16*)alloc(4096ull*1536*2);
  float* x0   = (float*)alloc(4096ull*768*4);
  u16*  x1    = (u16*)alloc(4096ull*768*2);
  u16*  hbuf  = (u16*)alloc(4096ull*3072*2);
  float* P    = (float*)qkvb;                  // 4 x 4096 x 768 f32 partial planes

  dim3 b256(256);
  wtrans_k<<<dim3(144,24),b256,0,stream>>>(wqkv, wqkvT, 768, 4608);
  wtrans_k<<<dim3(24,48),b256,0,stream>>>(wout, woutT, 1536, 768);
  wtrans_k<<<dim3(96,24),b256,0,stream>>>(wm1, wm1T, 768, 3072);
  wtrans_k<<<dim3(24,96),b256,0,stream>>>(wm2, wm2T, 3072, 768);
  ln1_k<<<4096,b256,0,stream>>>(x, ln1s, xin);
  gemm_k<3,1><<<dim3(36,32),b256,0,stream>>>(xin, wqkvT, 4096, 4608, 768, nullptr, qkvb, nullptr);
  postproc_k<<<4096,b256,0,stream>>>(qkvb, sincos, aq, ak, aqs, aks, qg,kg,vg,qsg,ksg,vsg);
  attn4_k<<<1536,b256,0,stream>>>(qg,kg,vg, qsg,ksg,vsg, cat, patch);
  gemm_k<0,4><<<dim3(6,32,4),b256,0,stream>>>(cat, woutT, 4096, 768, 1536, P, nullptr, nullptr);
  redln_k<<<4096,b256,0,stream>>>(P, bout, ls1, x, ln2s, ln2b, x0, x1);
  gemm_k<2,1><<<dim3(24,32),b256,0,stream>>>(x1, wm1T, 4096, 3072, 768, nullptr, hbuf, bm1);
  gemm_k<0,4><<<dim3(6,32,4),b256,0,stream>>>(hbuf, wm2T, 4096, 768, 3072, P, nullptr, nullptr);
  red_k<<<3072,b256,0,stream>>>(P, bm2, ls2, x0, out);
}

// Round 6
// 267.277 us; speedup vs baseline: 1.4679x; 1.1636x over previous
//
#include <hip/hip_runtime.h>

#define DEVI __device__ __forceinline__

typedef __attribute__((ext_vector_type(8))) short short8;
typedef __attribute__((ext_vector_type(4))) float f32x4;
typedef unsigned short u16;

DEVI u16 f2bf(float f){
  unsigned int u = __float_as_uint(f);
  unsigned int r = (u + 0x7FFFu + ((u>>16)&1u)) >> 16;
  return (u16)r;
}
DEVI float bf2f(u16 h){ return __uint_as_float(((unsigned int)h)<<16); }

DEVI float gelu_f(float x){
  float x3 = x*x*x;
  float t = tanhf(0.7978845608028654f*(x + 0.044715f*x3));
  return 0.5f*x*(1.0f + t);
}

DEVI void async_cp16(const void* g, void* l){
  __builtin_amdgcn_global_load_lds(
      (const __attribute__((address_space(1))) unsigned int*)g,
      (__attribute__((address_space(3))) unsigned int*)l, 16, 0, 0);
}

// ---------------- weight transpose + bf16 convert: w (K x N) f32 -> wt (N x K) bf16
__global__ __launch_bounds__(256) void wtrans_k(const float* __restrict__ w,
                                                u16* __restrict__ wt, int K, int N){
  __shared__ float tile[32][33];
  int tn = blockIdx.x*32, tk = blockIdx.y*32;
  int r = threadIdx.x>>3, c4 = (threadIdx.x&7)*4;
  float4 vv = *(const float4*)&w[(size_t)(tk+r)*N + tn + c4];
  tile[r][c4+0]=vv.x; tile[r][c4+1]=vv.y; tile[r][c4+2]=vv.z; tile[r][c4+3]=vv.w;
  __syncthreads();
  u16 o[4];
  #pragma unroll
  for (int j=0;j<4;j++) o[j] = f2bf(tile[c4+j][r]);
  unsigned long long pk = (unsigned long long)o[0] | ((unsigned long long)o[1]<<16)
                        | ((unsigned long long)o[2]<<32) | ((unsigned long long)o[3]<<48);
  *(unsigned long long*)&wt[(size_t)(tn+r)*K + tk + c4] = pk;
}

// ---------------- LN1: x f32 (4096x768) -> xin bf16
__global__ __launch_bounds__(256) void ln1_k(const float* __restrict__ x,
                                             const float* __restrict__ sc,
                                             u16* __restrict__ xin){
  int row = blockIdx.x, tid = threadIdx.x;
  const float* xr = x + (size_t)row*768;
  float v[3]; float s=0.f, ss=0.f;
  #pragma unroll
  for (int i=0;i<3;i++){ v[i]=xr[tid+i*256]; s+=v[i]; ss+=v[i]*v[i]; }
  #pragma unroll
  for (int m=1;m<=32;m<<=1){ s += __shfl_xor(s,m,64); ss += __shfl_xor(ss,m,64); }
  __shared__ float ls0[4], ls1_[4];
  int w = tid>>6;
  if ((tid&63)==0){ ls0[w]=s; ls1_[w]=ss; }
  __syncthreads();
  s = ls0[0]+ls0[1]+ls0[2]+ls0[3]; ss = ls1_[0]+ls1_[1]+ls1_[2]+ls1_[3];
  float mu = s*(1.f/768.f);
  float var = ss*(1.f/768.f) - mu*mu;
  float inv = rsqrtf(var + 1e-6f);
  #pragma unroll
  for (int i=0;i<3;i++){ int c=tid+i*256; xin[(size_t)row*768+c] = f2bf((v[i]-mu)*inv*sc[c]); }
}

// ---------------- GEMM: C(MxN) = A(MxK,bf16) * Bt(NxK,bf16)^T
// EPI 0: f32 partial plane (split-K)   EPI 2: bf16(gelu(acc+bias))   EPI 3: plain bf16
template<int EPI, int SPLITK>
__global__ __launch_bounds__(256) void gemm_k(
    const u16* __restrict__ A, const u16* __restrict__ Bt,
    int M, int N, int K,
    float* __restrict__ Cf, u16* __restrict__ Cb,
    const float* __restrict__ bias)
{
  __shared__ __align__(16) u16 Al[128*32];
  __shared__ __align__(16) u16 Bl[128*32];
  const int tid = threadIdx.x, w = tid>>6, l = tid&63;
  const int m0 = blockIdx.y*128, n0 = blockIdx.x*128;
  const int Ksub = K/SPLITK;
  const int kc = (SPLITK>1) ? blockIdx.z : 0;
  const int kbase = kc*Ksub;
  const int wr = (w>>1)*64, wc = (w&1)*64;
  f32x4 acc[4][4];
  #pragma unroll
  for (int i=0;i<4;i++)
    #pragma unroll
    for (int j=0;j<4;j++){ f32x4 z={0.f,0.f,0.f,0.f}; acc[i][j]=z; }
  const int lr = l>>2, lc = l&3;
  for (int k0=0; k0<Ksub; k0+=32){
    __syncthreads();
    #pragma unroll
    for (int it=0; it<2; ++it){
      int arow = w*32 + it*16;
      async_cp16(A  + (size_t)(m0+arow+lr)*K + kbase + k0 + lc*8, &Al[arow*32]);
      async_cp16(Bt + (size_t)(n0+arow+lr)*K + kbase + k0 + lc*8, &Bl[arow*32]);
    }
    __syncthreads();
    short8 af[4], bfr[4];
    #pragma unroll
    for (int mi=0;mi<4;++mi) af[mi]  = *(const short8*)&Al[(wr+mi*16+(l&15))*32 + (l>>4)*8];
    #pragma unroll
    for (int ni=0;ni<4;++ni) bfr[ni] = *(const short8*)&Bl[(wc+ni*16+(l&15))*32 + (l>>4)*8];
    #pragma unroll
    for (int mi=0;mi<4;++mi)
      #pragma unroll
      for (int ni=0;ni<4;++ni)
        acc[mi][ni] = __builtin_amdgcn_mfma_f32_16x16x32_bf16(af[mi], bfr[ni], acc[mi][ni], 0,0,0);
  }
  #pragma unroll
  for (int mi=0;mi<4;++mi){
    int rb = m0 + wr + mi*16 + ((l>>4)<<2);
    #pragma unroll
    for (int ni=0;ni<4;++ni){
      int col = n0 + wc + ni*16 + (l&15);
      #pragma unroll
      for (int r=0;r<4;r++){
        int row = rb + r;
        float v = acc[mi][ni][r];
        if (EPI==0)      Cf[((size_t)kc*M + row)*N + col] = v;
        else if (EPI==2) Cb[(size_t)row*N+col] = f2bf(gelu_f(v + bias[col]));
        else             Cb[(size_t)row*N+col] = f2bf(v);
      }
    }
  }
}

// ---------------- split-K reduce + bias/ls/resid + LN2 + gelu (out-proj path)
__global__ __launch_bounds__(256) void redln_k(
    const float* __restrict__ P, const float* __restrict__ bias,
    const float* __restrict__ lsc, const float* __restrict__ resid,
    const float* __restrict__ ln2sc, const float* __restrict__ ln2bi,
    float* __restrict__ x0, u16* __restrict__ x1)
{
  const size_t MN = 4096ull*768;
  int row = blockIdx.x, tid = threadIdx.x;
  float v[3]; float s=0.f, ss=0.f;
  #pragma unroll
  for (int i=0;i<3;i++){
    int c = tid + i*256;
    size_t idx = (size_t)row*768 + c;
    float acc = P[idx] + P[MN+idx] + P[2*MN+idx] + P[3*MN+idx];
    float y = lsc[c]*(acc + bias[c]) + resid[idx];
    x0[idx] = y;
    v[i] = y; s += y; ss += y*y;
  }
  #pragma unroll
  for (int m=1;m<=32;m<<=1){ s += __shfl_xor(s,m,64); ss += __shfl_xor(ss,m,64); }
  __shared__ float ls0[4], ls1_[4];
  int w = tid>>6;
  if ((tid&63)==0){ ls0[w]=s; ls1_[w]=ss; }
  __syncthreads();
  s = ls0[0]+ls0[1]+ls0[2]+ls0[3]; ss = ls1_[0]+ls1_[1]+ls1_[2]+ls1_[3];
  float mu = s*(1.f/768.f);
  float var = ss*(1.f/768.f) - mu*mu;
  float inv = rsqrtf(var + 1e-6f);
  #pragma unroll
  for (int i=0;i<3;i++){
    int c = tid + i*256;
    float y = (v[i]-mu)*inv*ln2sc[c] + ln2bi[c];
    x1[(size_t)row*768 + c] = f2bf(gelu_f(y));
  }
}

// ---------------- split-K reduce + bias/ls/resid (final output)
__global__ __launch_bounds__(256) void red_k(
    const float* __restrict__ P, const float* __restrict__ bias,
    const float* __restrict__ lsc, const float* __restrict__ resid,
    float* __restrict__ out)
{
  const size_t MN = 4096ull*768;
  size_t i = ((size_t)blockIdx.x*256 + threadIdx.x)*4;
  int c = (int)(i % 768);
  float4 a0 = *(const float4*)&P[i];
  float4 a1 = *(const float4*)&P[MN+i];
  float4 a2 = *(const float4*)&P[2*MN+i];
  float4 a3 = *(const float4*)&P[3*MN+i];
  float4 bi = *(const float4*)&bias[c];
  float4 ls = *(const float4*)&lsc[c];
  float4 rs = *(const float4*)&resid[i];
  float4 o;
  o.x = ls.x*(a0.x+a1.x+a2.x+a3.x + bi.x) + rs.x;
  o.y = ls.y*(a0.y+a1.y+a2.y+a3.y + bi.y) + rs.y;
  o.z = ls.z*(a0.z+a1.z+a2.z+a3.z + bi.z) + rs.z;
  o.w = ls.w*(a0.w+a1.w+a2.w+a3.w + bi.w) + rs.w;
  *(float4*)&out[i] = o;
}

// ---------------- qkv postprocess v2: tile kernel, rms+rope in-register,
// V transposed through padded LDS so ALL global writes are coalesced.
// grid: 768 = (b:2)*(v:4)*(t6:8)*(h:12). lane = (tq=l>>4, dq=l&15) holds d-quad.
__global__ __launch_bounds__(256) void postproc2_k(
  const u16* __restrict__ qkv, const float* __restrict__ sincos,
  const float* __restrict__ aq, const float* __restrict__ ak,
  const float* __restrict__ aqs, const float* __restrict__ aks,
  u16* __restrict__ qg, u16* __restrict__ kg, u16* __restrict__ vg,
  u16* __restrict__ qsg, u16* __restrict__ ksg, u16* __restrict__ vsg)
{
  __shared__ u16 vt[2][64*66];   // [t][d] padded: row stride 66 u16 (132 B)
  const int bid = blockIdx.x;
  const int b = bid/384; int r0 = bid - b*384;
  const int v = r0/96;   int r1 = r0 - v*96;
  const int t6 = r1/12;  const int h = r1 - t6*12;
  const int T0 = t6*64;
  const int tid = threadIdx.x, w = tid>>6, l = tid&63;
  const int tq = l>>4, dq = l&15;
  const int m0 = b*2048 + v*512;
  const size_t gQbase = ((size_t)(b*12) + h)*2048 + v*512;
  const size_t sQbase = ((size_t)((v*2+b)*12) + h)*512;

  // ---- q / k / qs / ks: rms + rope, row-coalesced writes
  #pragma unroll
  for (int qi=0; qi<4; ++qi){
    const int tt = (qi<2) ? qi : qi+1;          // 0,1,3,4
    const float* al = (qi==0)?aq:(qi==1)?ak:(qi==2)?aqs:aks;
    float4 alv = *(const float4*)&al[h*64 + dq*4];
    u16* dst = (qi==0)?qg:(qi==1)?kg:(qi==2)?qsg:ksg;
    const size_t obase = (qi<2) ? gQbase : sQbase;
    #pragma unroll
    for (int it=0; it<4; ++it){
      const int t = T0 + w*16 + it*4 + tq;
      const u16* src = &qkv[(size_t)(m0+t)*4608 + tt*768 + h*64 + dq*4];
      ushort2 u01 = *(const ushort2*)src;
      ushort2 u23 = *(const ushort2*)(src+2);
      float x0=bf2f(u01.x), x1=bf2f(u01.y), x2=bf2f(u23.x), x3=bf2f(u23.y);
      float ss = x0*x0+x1*x1+x2*x2+x3*x3;
      #pragma unroll
      for (int mm=1;mm<=8;mm<<=1) ss += __shfl_xor(ss,mm,64);
      float rinv = rsqrtf(ss*(1.f/64.f) + 1e-5f);
      x0 *= alv.x*rinv; x1 *= alv.y*rinv; x2 *= alv.z*rinv; x3 *= alv.w*rinv;
      float4 cs01 = *(const float4*)&sincos[(size_t)(t*64 + dq*4)*2];
      float4 cs23 = *(const float4*)&sincos[(size_t)(t*64 + dq*4)*2 + 4];
      float y0 = x0*cs01.x - x1*cs01.y;
      float y1 = x1*cs01.z + x0*cs01.w;
      float y2 = x2*cs23.x - x3*cs23.y;
      float y3 = x3*cs23.z + x2*cs23.w;
      unsigned int lo = (unsigned int)f2bf(y0) | ((unsigned int)f2bf(y1)<<16);
      unsigned int hi = (unsigned int)f2bf(y2) | ((unsigned int)f2bf(y3)<<16);
      unsigned int* po = (unsigned int*)&dst[(obase + t)*64 + dq*4];
      po[0] = lo; po[1] = hi;
    }
  }

  // ---- v / vs: stage [t][d] tiles in LDS, write transposed [d][t] coalesced
  #pragma unroll
  for (int vi=0; vi<2; ++vi){
    const int tt = (vi==0) ? 2 : 5;
    #pragma unroll
    for (int it=0; it<4; ++it){
      const int t = T0 + w*16 + it*4 + tq;
      const int tl = w*16 + it*4 + tq;
      const u16* src = &qkv[(size_t)(m0+t)*4608 + tt*768 + h*64 + dq*4];
      ushort2 u01 = *(const ushort2*)src;
      ushort2 u23 = *(const ushort2*)(src+2);
      unsigned int* pl = (unsigned int*)&vt[vi][tl*66 + dq*4];
      pl[0] = (unsigned int)u01.x | ((unsigned int)u01.y<<16);
      pl[1] = (unsigned int)u23.x | ((unsigned int)u23.y<<16);
    }
  }
  __syncthreads();
  {
    // global V: [ (b*12+h)*64 + d ]*2048 + v*512 + T0 + l
    const size_t vgb = (((size_t)(b*12) + h)*64)*2048 + v*512 + T0 + l;
    #pragma unroll
    for (int i=0;i<16;++i){
      int d = w*16 + i;
      vg[vgb + (size_t)d*2048] = vt[0][l*66 + d];
    }
    // shifted V: [ ((v*2+b)*12+h)*64 + d ]*512 + T0 + l
    const size_t vsb = (((size_t)((v*2+b)*12) + h)*64)*512 + T0 + l;
    #pragma unroll
    for (int i=0;i<16;++i){
      int d = w*16 + i;
      vsg[vsb + (size_t)d*512] = vt[1][l*66 + d];
    }
  }
}

// ---------------- merged segment-masked flash attention (one launch)
// Q/K: [seq][h][L][64] bf16 ; Vt: [seq][h][64][L] bf16 ; Out bf16 [4096][1536]
// NO online max: scores provably bounded (|s|<=8 from rms-norm'd q,k), so
// p = exp(s) directly -> no rescale, per-lane lsum reduced once at the end.
// K/Vt double-buffered in LDS, reg-staged prefetch (T14), 1 barrier/tile.
__global__ __launch_bounds__(256) void attn4_k(
  const u16* __restrict__ Qg, const u16* __restrict__ Kg, const u16* __restrict__ Vtg,
  const u16* __restrict__ Qs, const u16* __restrict__ Ks, const u16* __restrict__ Vts,
  u16* __restrict__ Out, const int* __restrict__ pids)
{
  __shared__ __align__(16) u16 Kl[2][64*64];
  __shared__ __align__(16) u16 Vl[2][64*64];
  __shared__ __align__(16) u16 Pl[4][16*64];
  __shared__ unsigned long long amask_s;
  const int gid = blockIdx.x;
  // balanced XCD swizzle: each XCD gets 96 global + 96 shifted contiguous blocks
  const int xcd = gid & 7, idx = gid >> 3;
  const int lid = (idx < 96) ? xcd*96 + idx : 768 + xcd*96 + (idx - 96);
  const int tid = threadIdx.x, w = tid>>6, l = tid&63;
  const u16 *Q, *K, *Vt; const int* prow;
  int L, seq, h, qb, orow0, ocol;
  if (lid < 768){
    seq = lid/384; int rem2 = lid - seq*384; h = rem2>>5; qb = rem2&31;
    Q=Qg; K=Kg; Vt=Vtg; L=2048;
    prow = pids + seq*512; orow0 = seq*2048; ocol = h*64;
  } else {
    int g2 = lid - 768; seq = g2/96; int rem2 = g2 - seq*96; h = rem2>>3; qb = rem2&7;
    Q=Qs; K=Ks; Vt=Vts; L=512;
    prow = pids + (seq&1)*512; orow0 = (seq&1)*2048 + (seq>>1)*512; ocol = 768 + h*64;
  }
  const size_t base = ((size_t)(seq*12) + h)*(size_t)L*64;
  const int q0 = qb*64, tq0 = q0 & 511;
  short8 qf[2];
  const int qrow = q0 + w*16 + (l&15);
  #pragma unroll
  for (int s=0;s<2;s++) qf[s] = *(const short8*)&Q[base + (size_t)qrow*64 + s*32 + (l>>4)*8];
  const int qlo = prow[tq0], qhi = prow[tq0+63];
  int sq[4];
  #pragma unroll
  for (int r=0;r<4;r++) sq[r] = prow[tq0 + w*16 + (l>>4)*4 + r];
  float lsum[4]; f32x4 ao[4];
  #pragma unroll
  for (int r=0;r<4;r++) lsum[r]=0.f;
  #pragma unroll
  for (int d=0;d<4;d++){ f32x4 z={0.f,0.f,0.f,0.f}; ao[d]=z; }
  const int nk = L/64;
  // ---- active-tile bitmask (uniform): wave 0 ballots over segment ranges
  bool act = false;
  if (tid < 64 && tid < nk){
    int tk0 = (tid*64)&511;
    act = (prow[tk0+63] >= qlo) && (prow[tk0] <= qhi);
  }
  unsigned long long bm = __ballot(act);
  if (tid==0) amask_s = bm;
  __syncthreads();
  unsigned long long rem = amask_s;   // non-empty: diagonal tile always active
  int t = (int)(__ffsll((unsigned long long)rem)-1); rem &= rem-1;
  uint4 kr[2], vr[2];
  {  // prologue: stage first tile
    int k0 = t*64;
    #pragma unroll
    for (int it=0;it<2;++it){
      int slot=it*256+tid, row=slot>>3, c16=slot&7;
      kr[it] = *(const uint4*)&K[base + (size_t)(k0+row)*64 + c16*8];
      vr[it] = *(const uint4*)&Vt[base + (size_t)row*(size_t)L + k0 + c16*8];
    }
    #pragma unroll
    for (int it=0;it<2;++it){
      int slot=it*256+tid, row=slot>>3, c16=slot&7;
      int boff = row*128 + ((c16*16) ^ ((row&7)<<4));
      *(uint4*)((char*)&Kl[0][0] + boff) = kr[it];
      *(uint4*)((char*)&Vl[0][0] + boff) = vr[it];
    }
  }
  __syncthreads();
  int cur = 0;
  while (true){
    int tn = rem ? (int)(__ffsll((unsigned long long)rem)-1) : -1;
    if (tn >= 0){           // issue next tile's loads now; they land during compute
      rem &= rem-1;
      int k0n = tn*64;
      #pragma unroll
      for (int it=0;it<2;++it){
        int slot=it*256+tid, row=slot>>3, c16=slot&7;
        kr[it] = *(const uint4*)&K[base + (size_t)(k0n+row)*64 + c16*8];
        vr[it] = *(const uint4*)&Vt[base + (size_t)row*(size_t)L + k0n + c16*8];
      }
    }
    // ---- compute current tile from LDS
    const int tk0 = (t*64) & 511;
    const u16* Kb = &Kl[cur][0];
    const u16* Vb = &Vl[cur][0];
    f32x4 s4[4];
    #pragma unroll
    for (int kb=0;kb<4;kb++){
      const int krow = kb*16 + (l&15);
      f32x4 a = {0.f,0.f,0.f,0.f};
      #pragma unroll
      for (int s=0;s<2;s++){
        int boff = krow*128 + ((s*64 + (l>>4)*16) ^ ((krow&7)<<4));
        short8 kf = *(const short8*)((const char*)Kb + boff);
        a = __builtin_amdgcn_mfma_f32_16x16x32_bf16(qf[s], kf, a, 0,0,0);
      }
      s4[kb] = a;
    }
    // ---- mask + direct exp (no max subtraction: |s*0.125| <= 8)
    float pv[4][4];
    #pragma unroll
    for (int kb=0;kb<4;kb++){
      int sk = prow[tk0 + kb*16 + (l&15)];
      #pragma unroll
      for (int r=0;r<4;r++){
        float p = (sk == sq[r]) ? __expf(s4[kb][r]*0.125f) : 0.f;
        pv[kb][r] = p;
        lsum[r] += p;          // per-lane partial; reduced once at the end
      }
    }
    // ---- P fragment relayout via per-wave LDS (no barrier: wave-private slice)
    #pragma unroll
    for (int kb=0;kb<4;kb++)
      #pragma unroll
      for (int r=0;r<4;r++){
        int prw = (l>>4)*4 + r;
        Pl[w][prw*64 + (((kb*32 + (l&15)*2) ^ ((prw&7)<<4))>>1)] = f2bf(pv[kb][r]);
      }
    short8 pa[2];
    #pragma unroll
    for (int s=0;s<2;s++)
      pa[s] = *(const short8*)&Pl[w][(l&15)*64 + (((s*64 + (l>>4)*16) ^ (((l&15)&7)<<4))>>1)];
    #pragma unroll
    for (int d=0;d<4;d++){
      const int vrow = d*16 + (l&15);
      #pragma unroll
      for (int s=0;s<2;s++){
        int boff = vrow*128 + ((s*64 + (l>>4)*16) ^ ((vrow&7)<<4));
        short8 vf = *(const short8*)((const char*)Vb + boff);
        ao[d] = __builtin_amdgcn_mfma_f32_16x16x32_bf16(pa[s], vf, ao[d], 0,0,0);
      }
    }
    if (tn < 0) break;
    // ---- stage next tile into the other buffer
    #pragma unroll
    for (int it=0;it<2;++it){
      int slot=it*256+tid, row=slot>>3, c16=slot&7;
      int boff = row*128 + ((c16*16) ^ ((row&7)<<4));
      *(uint4*)((char*)&Kl[cur^1][0] + boff) = kr[it];
      *(uint4*)((char*)&Vl[cur^1][0] + boff) = vr[it];
    }
    __syncthreads();
    cur ^= 1; t = tn;
  }
  // ---- final row-sum reduce (16 lanes share a row-group)
  #pragma unroll
  for (int r=0;r<4;r++){
    #pragma unroll
    for (int m=1;m<=8;m<<=1) lsum[r] += __shfl_xor(lsum[r], m, 64);
  }
  #pragma unroll
  for (int d=0;d<4;d++){
    int col = ocol + d*16 + (l&15);
    #pragma unroll
    for (int r=0;r<4;r++){
      int row = orow0 + q0 + w*16 + (l>>4)*4 + r;
      Out[(size_t)row*1536 + col] = f2bf(ao[d][r] / lsum[r]);
    }
  }
}

extern "C" void kernel_launch(void* const* d_in, const int* in_sizes, int n_in,
                              void* d_out, int out_size, void* d_ws, size_t ws_size,
                              hipStream_t stream) {
  const float* x      = (const float*)d_in[0];
  const int*   patch  = (const int*)d_in[1];
  const float* sincos = (const float*)d_in[2];
  const float* ln1s   = (const float*)d_in[3];
  const float* wqkv   = (const float*)d_in[4];
  const float* aq     = (const float*)d_in[5];
  const float* ak     = (const float*)d_in[6];
  const float* aqs    = (const float*)d_in[7];
  const float* aks    = (const float*)d_in[8];
  const float* wout   = (const float*)d_in[9];
  const float* bout   = (const float*)d_in[10];
  const float* ls1    = (const float*)d_in[11];
  const float* ln2s   = (const float*)d_in[12];
  const float* ln2b   = (const float*)d_in[13];
  const float* wm1    = (const float*)d_in[14];
  const float* bm1    = (const float*)d_in[15];
  const float* wm2    = (const float*)d_in[16];
  const float* bm2    = (const float*)d_in[17];
  const float* ls2    = (const float*)d_in[18];
  float* out = (float*)d_out;

  char* ws = (char*)d_ws;
  size_t off = 0;
  auto alloc = [&](size_t bytes)->void*{ void* p = ws + off; off += (bytes + 255) & ~(size_t)255; return p; };
  u16*  wqkvT = (u16*)alloc(4608ull*768*2);
  u16*  woutT = (u16*)alloc(768ull*1536*2);
  u16*  wm1T  = (u16*)alloc(3072ull*768*2);
  u16*  wm2T  = (u16*)alloc(768ull*3072*2);
  u16*  xin   = (u16*)alloc(4096ull*768*2);
  u16*  qkvb  = (u16*)alloc(4096ull*4608*2);   // bf16 qkv; ALSO aliased by split-K partials P
  u16*  qg    = (u16*)alloc(3145728ull*2);     // (P spans qkvb+qg+kg = 50,331,648 B exactly)
  u16*  kg    = (u16*)alloc(3145728ull*2);
  u16*  vg    = (u16*)alloc(3145728ull*2);     // transposed [2][12][64][2048]
  u16*  qsg   = (u16*)alloc(3145728ull*2);
  u16*  ksg   = (u16*)alloc(3145728ull*2);
  u16*  vsg   = (u16*)alloc(3145728ull*2);     // transposed [8][12][64][512]
  u16*  cat   = (u16*)alloc(4096ull*1536*2);
  float* x0   = (float*)alloc(4096ull*768*4);
  u16*  x1    = (u16*)alloc(4096ull*768*2);
  u16*  hbuf  = (u16*)alloc(4096ull*3072*2);
  float* P    = (float*)qkvb;                  // 4 x 4096 x 768 f32 partial planes

  dim3 b256(256);
  wtrans_k<<<dim3(144,24),b256,0,stream>>>(wqkv, wqkvT, 768, 4608);
  wtrans_k<<<dim3(24,48),b256,0,stream>>>(wout, woutT, 1536, 768);
  wtrans_k<<<dim3(96,24),b256,0,stream>>>(wm1, wm1T, 768, 3072);
  wtrans_k<<<dim3(24,96),b256,0,stream>>>(wm2, wm2T, 3072, 768);
  ln1_k<<<4096,b256,0,stream>>>(x, ln1s, xin);
  gemm_k<3,1><<<dim3(36,32),b256,0,stream>>>(xin, wqkvT, 4096, 4608, 768, nullptr, qkvb, nullptr);
  postproc2_k<<<768,b256,0,stream>>>(qkvb, sincos, aq, ak, aqs, aks, qg,kg,vg,qsg,ksg,vsg);
  attn4_k<<<1536,b256,0,stream>>>(qg,kg,vg, qsg,ksg,vsg, cat, patch);
  gemm_k<0,4><<<dim3(6,32,4),b256,0,stream>>>(cat, woutT, 4096, 768, 1536, P, nullptr, nullptr);
  redln_k<<<4096,b256,0,stream>>>(P, bout, ls1, x, ln2s, ln2b, x0, x1);
  gemm_k<2,1><<<dim3(24,32),b256,0,stream>>>(x1, wm1T, 4096, 3072, 768, nullptr, hbuf, bm1);
  gemm_k<0,4><<<dim3(6,32,4),b256,0,stream>>>(hbuf, wm2T, 4096, 768, 3072, P, nullptr, nullptr);
  red_k<<<3072,b256,0,stream>>>(P, bm2, ls2, x0, out);
}